// Round 1
// baseline (5099.030 us; speedup 1.0000x reference)
//
#include <hip/hip_runtime.h>
#include <hip/hip_bf16.h>
#include <math.h>

#define NN 100000
#define EE 1600000
#define DD 128
#define HH 8

// native fp32 atomic add (global_atomic_add_f32); denorm-flush is fine here
__device__ __forceinline__ void atomAddF(float* p, float v) {
    unsafeAtomicAdd(p, v);
}

// ---------------------------------------------------------------------------
// Fold rel_att/rel_msg into Wk/Wv and transpose all weights to [c][j] layout
// so the GEMM loads them into LDS coalesced & conflict-free.
// which: 0=q transpose, 1=k fold+transpose, 2=v fold+transpose, 3=a transpose
// ---------------------------------------------------------------------------
__global__ void prep_weights(const float* __restrict__ Wq, const float* __restrict__ Wk,
                             const float* __restrict__ Wv, const float* __restrict__ Wa,
                             const float* __restrict__ bk, const float* __restrict__ bv,
                             const float* __restrict__ rel_att, const float* __restrict__ rel_msg,
                             float* __restrict__ WqT, float* __restrict__ WkT,
                             float* __restrict__ WvT, float* __restrict__ WaT,
                             float* __restrict__ bk_eff, float* __restrict__ bv_eff) {
    int o = blockIdx.x * 256 + threadIdx.x;   // 0..16383 over [c][j]
    int c = o >> 7, j = o & 127;
    int which = blockIdx.y;
    if (which == 0) {
        WqT[o] = Wq[j * 128 + c];
    } else if (which == 3) {
        WaT[o] = Wa[j * 128 + c];
    } else {
        const float* rel = (which == 1) ? rel_att : rel_msg;
        const float* W   = (which == 1) ? Wk : Wv;
        const float* b   = (which == 1) ? bk : bv;
        float* WT        = (which == 1) ? WkT : WvT;
        float* be        = (which == 1) ? bk_eff : bv_eff;
        int hh = j >> 4, e = j & 15;
        float acc = 0.f;
        #pragma unroll
        for (int d = 0; d < 16; d++)
            acc += rel[hh * 256 + d * 16 + e] * W[(hh * 16 + d) * 128 + c];
        WT[o] = acc;
        if (c == 0) {
            float bacc = 0.f;
            #pragma unroll
            for (int d = 0; d < 16; d++)
                bacc += b[hh * 16 + d] * rel[hh * 256 + d * 16 + e];
            be[j] = bacc;
        }
    }
}

// ---------------------------------------------------------------------------
// y[N,128] = x[N,128] @ W.T + bias, with WT given as [c][j].
// If resid != nullptr: y = alpha*(x@W.T+bias) + (1-alpha)*resid, alpha=sigmoid(skip).
// W (64KB) lives in LDS; x staged in 64x32 chunks; 8 rows x 4 cols per thread.
// ---------------------------------------------------------------------------
__launch_bounds__(256, 2)
__global__ void gemm128(const float* __restrict__ x, const float* __restrict__ WT,
                        const float* __restrict__ bias, float* __restrict__ y,
                        const float* __restrict__ resid, const float* __restrict__ skip) {
    __shared__ float Wl[128 * 128];
    __shared__ float xl[64 * 32];
    int tid = threadIdx.x;
    for (int i = tid * 4; i < 16384; i += 1024)
        *(float4*)&Wl[i] = *(const float4*)&WT[i];

    int lane = tid & 31, rowg = tid >> 5;
    int col4 = lane * 4;
    float4 bv4 = *(const float4*)&bias[col4];
    float alpha = 1.f, beta = 0.f;
    if (resid) {
        float sv = skip[0];
        alpha = 1.f / (1.f + expf(-sv));
        beta = 1.f - alpha;
    }
    __syncthreads();

    for (int base = blockIdx.x * 64; base < NN; base += gridDim.x * 64) {
        float acc[8][4];
        #pragma unroll
        for (int i = 0; i < 8; i++)
            acc[i][0] = acc[i][1] = acc[i][2] = acc[i][3] = 0.f;

        for (int cb = 0; cb < 128; cb += 32) {
            __syncthreads();
            #pragma unroll
            for (int f = tid; f < 2048; f += 256) {
                int r = f >> 5, cc = f & 31;
                int row = base + r;
                xl[f] = (row < NN) ? x[(size_t)row * 128 + cb + cc] : 0.f;
            }
            __syncthreads();
            for (int ci = 0; ci < 32; ci++) {
                float4 w = *(const float4*)&Wl[(cb + ci) * 128 + col4];
                #pragma unroll
                for (int i = 0; i < 8; i++) {
                    float xv = xl[(rowg * 8 + i) * 32 + ci];
                    acc[i][0] = fmaf(xv, w.x, acc[i][0]);
                    acc[i][1] = fmaf(xv, w.y, acc[i][1]);
                    acc[i][2] = fmaf(xv, w.z, acc[i][2]);
                    acc[i][3] = fmaf(xv, w.w, acc[i][3]);
                }
            }
        }
        #pragma unroll
        for (int i = 0; i < 8; i++) {
            int row = base + rowg * 8 + i;
            if (row < NN) {
                float4 o;
                o.x = acc[i][0] + bv4.x;
                o.y = acc[i][1] + bv4.y;
                o.z = acc[i][2] + bv4.z;
                o.w = acc[i][3] + bv4.w;
                if (resid) {
                    float4 r4 = *(const float4*)&resid[(size_t)row * 128 + col4];
                    o.x = alpha * o.x + beta * r4.x;
                    o.y = alpha * o.y + beta * r4.y;
                    o.z = alpha * o.z + beta * r4.z;
                    o.w = alpha * o.w + beta * r4.w;
                }
                *(float4*)&y[(size_t)row * 128 + col4] = o;
            }
        }
    }
}

// ---------------------------------------------------------------------------
// Per (edge, head): score = dot(q[dst,h,:], k[src,h,:]) * rel_pri[h] / sqrt(16)
// ex = exp(score)  (no max-subtraction needed: |score| is O(1..8), exp is safe
// and attn = ex/denom is mathematically identical to the max-shifted form)
// ---------------------------------------------------------------------------
__global__ void edge_score(const float* __restrict__ q, const float* __restrict__ k,
                           const int* __restrict__ src, const int* __restrict__ dst,
                           const float* __restrict__ rel_pri,
                           float* __restrict__ ex, float* __restrict__ denom) {
    long long idx = (long long)blockIdx.x * 256 + threadIdx.x;
    if (idx >= (long long)EE * HH) return;
    int e  = (int)(idx >> 3);
    int hh = (int)(idx & 7);
    int s = src[e], d = dst[e];
    const float4* qp = (const float4*)(q + (size_t)d * 128 + hh * 16);
    const float4* kp = (const float4*)(k + (size_t)s * 128 + hh * 16);
    float acc = 0.f;
    #pragma unroll
    for (int j = 0; j < 4; j++) {
        float4 a = qp[j], b = kp[j];
        acc += a.x * b.x + a.y * b.y + a.z * b.z + a.w * b.w;
    }
    float sc = acc * rel_pri[hh] * 0.25f;
    float ev = expf(sc);
    ex[idx] = ev;
    atomAddF(&denom[(size_t)d * 8 + hh], ev);
}

// ---------------------------------------------------------------------------
// Per (edge, 4 elems): t[dst, d4] += v[src, d4] * (ex[e,h]/denom[dst,h])
// ---------------------------------------------------------------------------
__global__ void edge_aggregate(const float* __restrict__ v, const float* __restrict__ ex,
                               const float* __restrict__ denom,
                               const int* __restrict__ src, const int* __restrict__ dst,
                               float* __restrict__ t) {
    long long idx = (long long)blockIdx.x * 256 + threadIdx.x;
    if (idx >= (long long)EE * 32) return;
    int e = (int)(idx >> 5);
    int g = (int)(idx & 31);
    int hh = g >> 2;
    int s = src[e], d = dst[e];
    float attn = ex[(size_t)e * 8 + hh] / denom[(size_t)d * 8 + hh];
    float4 v4 = *(const float4*)&v[(size_t)s * 128 + g * 4];
    float* tp = t + (size_t)d * 128 + g * 4;
    atomAddF(tp + 0, v4.x * attn);
    atomAddF(tp + 1, v4.y * attn);
    atomAddF(tp + 2, v4.z * attn);
    atomAddF(tp + 3, v4.w * attn);
}

// ---------------------------------------------------------------------------
extern "C" void kernel_launch(void* const* d_in, const int* in_sizes, int n_in,
                              void* d_out, int out_size, void* d_ws, size_t ws_size,
                              hipStream_t stream) {
    const float* h    = (const float*)d_in[0];
    const int*   src  = (const int*)d_in[1];
    const int*   dst  = (const int*)d_in[2];
    const float* Wk   = (const float*)d_in[3];
    const float* bk   = (const float*)d_in[4];
    const float* Wq   = (const float*)d_in[5];
    const float* bq   = (const float*)d_in[6];
    const float* Wv   = (const float*)d_in[7];
    const float* bv   = (const float*)d_in[8];
    const float* Wa   = (const float*)d_in[9];
    const float* ba   = (const float*)d_in[10];
    const float* rel_att = (const float*)d_in[11];
    const float* rel_msg = (const float*)d_in[12];
    const float* rel_pri = (const float*)d_in[13];
    const float* skip    = (const float*)d_in[14];
    float* out = (float*)d_out;

    float* ws  = (float*)d_ws;
    float* q   = ws;                          // N*D   (later reused as t)
    float* kv  = q  + (size_t)NN * DD;        // N*D   (k, later v)
    float* exb = kv + (size_t)NN * DD;        // E*H
    float* den = exb + (size_t)EE * HH;       // N*H
    float* WqT = den + (size_t)NN * HH;       // D*D
    float* WkT = WqT + DD * DD;
    float* WvT = WkT + DD * DD;
    float* WaT = WvT + DD * DD;
    float* bke = WaT + DD * DD;               // D
    float* bve = bke + DD;                    // D
    float* t   = q;                           // reuse (q dead after edge_score)

    prep_weights<<<dim3(64, 4), 256, 0, stream>>>(Wq, Wk, Wv, Wa, bk, bv,
                                                  rel_att, rel_msg,
                                                  WqT, WkT, WvT, WaT, bke, bve);
    // q and k' projections
    gemm128<<<1024, 256, 0, stream>>>(h, WqT, bq, q, nullptr, nullptr);
    gemm128<<<1024, 256, 0, stream>>>(h, WkT, bke, kv, nullptr, nullptr);
    // edge scores + softmax denominators
    hipMemsetAsync(den, 0, (size_t)NN * HH * sizeof(float), stream);
    edge_score<<<(EE * HH) / 256, 256, 0, stream>>>(q, kv, src, dst, rel_pri, exb, den);
    // v' projection (overwrites k, which is now dead)
    gemm128<<<1024, 256, 0, stream>>>(h, WvT, bve, kv, nullptr, nullptr);
    // weighted scatter-aggregate into t (reuses q's buffer)
    hipMemsetAsync(t, 0, (size_t)NN * DD * sizeof(float), stream);
    edge_aggregate<<<(EE * 32) / 256, 256, 0, stream>>>(kv, exb, den, src, dst, t);
    // final projection + skip-gate mix
    gemm128<<<1024, 256, 0, stream>>>(t, WaT, ba, out, h, skip);
}

// Round 2
// 2628.305 us; speedup vs baseline: 1.9400x; 1.9400x over previous
//
#include <hip/hip_runtime.h>
#include <hip/hip_bf16.h>
#include <math.h>

#define NN 100000
#define EE 1600000
#define DD 128
#define HH 8
#define CAP 64   // LDS-cached edges per node (Poisson(16): P(deg>64) ~ 0; fallback recomputes)

// ---------------------------------------------------------------------------
// Fold rel_att/rel_msg into Wk/Wv and transpose all weights to [c][j] layout.
// which: 0=q transpose, 1=k fold+transpose, 2=v fold+transpose, 3=a transpose
// ---------------------------------------------------------------------------
__global__ void prep_weights(const float* __restrict__ Wq, const float* __restrict__ Wk,
                             const float* __restrict__ Wv, const float* __restrict__ Wa,
                             const float* __restrict__ bk, const float* __restrict__ bv,
                             const float* __restrict__ rel_att, const float* __restrict__ rel_msg,
                             float* __restrict__ WqT, float* __restrict__ WkT,
                             float* __restrict__ WvT, float* __restrict__ WaT,
                             float* __restrict__ bk_eff, float* __restrict__ bv_eff) {
    int o = blockIdx.x * 256 + threadIdx.x;   // 0..16383 over [c][j]
    int c = o >> 7, j = o & 127;
    int which = blockIdx.y;
    if (which == 0) {
        WqT[o] = Wq[j * 128 + c];
    } else if (which == 3) {
        WaT[o] = Wa[j * 128 + c];
    } else {
        const float* rel = (which == 1) ? rel_att : rel_msg;
        const float* W   = (which == 1) ? Wk : Wv;
        const float* b   = (which == 1) ? bk : bv;
        float* WT        = (which == 1) ? WkT : WvT;
        float* be        = (which == 1) ? bk_eff : bv_eff;
        int hh = j >> 4, e = j & 15;
        float acc = 0.f;
        #pragma unroll
        for (int d = 0; d < 16; d++)
            acc += rel[hh * 256 + d * 16 + e] * W[(hh * 16 + d) * 128 + c];
        WT[o] = acc;
        if (c == 0) {
            float bacc = 0.f;
            #pragma unroll
            for (int d = 0; d < 16; d++)
                bacc += b[hh * 16 + d] * rel[hh * 256 + d * 16 + e];
            be[j] = bacc;
        }
    }
}

// ---------------------------------------------------------------------------
// y[N,128] = x[N,128] @ W.T + bias (WT is [c][j]); optional skip-gate mix.
// In-place (y == x) is safe: each row-block is fully staged to LDS before
// its epilogue writes, and blocks own disjoint rows.
// ---------------------------------------------------------------------------
__launch_bounds__(256, 2)
__global__ void gemm128(const float* __restrict__ x, const float* __restrict__ WT,
                        const float* __restrict__ bias, float* __restrict__ y,
                        const float* __restrict__ resid, const float* __restrict__ skip) {
    __shared__ float Wl[128 * 128];
    __shared__ float xl[64 * 32];
    int tid = threadIdx.x;
    for (int i = tid * 4; i < 16384; i += 1024)
        *(float4*)&Wl[i] = *(const float4*)&WT[i];

    int lane = tid & 31, rowg = tid >> 5;
    int col4 = lane * 4;
    float4 bv4 = *(const float4*)&bias[col4];
    float alpha = 1.f, beta = 0.f;
    if (resid) {
        float sv = skip[0];
        alpha = 1.f / (1.f + expf(-sv));
        beta = 1.f - alpha;
    }
    __syncthreads();

    for (int base = blockIdx.x * 64; base < NN; base += gridDim.x * 64) {
        float acc[8][4];
        #pragma unroll
        for (int i = 0; i < 8; i++)
            acc[i][0] = acc[i][1] = acc[i][2] = acc[i][3] = 0.f;

        for (int cb = 0; cb < 128; cb += 32) {
            __syncthreads();
            #pragma unroll
            for (int f = tid; f < 2048; f += 256) {
                int r = f >> 5, cc = f & 31;
                int row = base + r;
                xl[f] = (row < NN) ? x[(size_t)row * 128 + cb + cc] : 0.f;
            }
            __syncthreads();
            for (int ci = 0; ci < 32; ci++) {
                float4 w = *(const float4*)&Wl[(cb + ci) * 128 + col4];
                #pragma unroll
                for (int i = 0; i < 8; i++) {
                    float xv = xl[(rowg * 8 + i) * 32 + ci];
                    acc[i][0] = fmaf(xv, w.x, acc[i][0]);
                    acc[i][1] = fmaf(xv, w.y, acc[i][1]);
                    acc[i][2] = fmaf(xv, w.z, acc[i][2]);
                    acc[i][3] = fmaf(xv, w.w, acc[i][3]);
                }
            }
        }
        #pragma unroll
        for (int i = 0; i < 8; i++) {
            int row = base + rowg * 8 + i;
            if (row < NN) {
                float4 o;
                o.x = acc[i][0] + bv4.x;
                o.y = acc[i][1] + bv4.y;
                o.z = acc[i][2] + bv4.z;
                o.w = acc[i][3] + bv4.w;
                if (resid) {
                    float4 r4 = *(const float4*)&resid[(size_t)row * 128 + col4];
                    o.x = alpha * o.x + beta * r4.x;
                    o.y = alpha * o.y + beta * r4.y;
                    o.z = alpha * o.z + beta * r4.z;
                    o.w = alpha * o.w + beta * r4.w;
                }
                *(float4*)&y[(size_t)row * 128 + col4] = o;
            }
        }
    }
}

// ------------------------- CSR build (counting sort) -----------------------
__global__ void hist_dst(const int* __restrict__ dst, int* __restrict__ deg) {
    int e = blockIdx.x * 256 + threadIdx.x;
    if (e < EE) atomicAdd(&deg[dst[e]], 1);
}

// block partial sums: 98 blocks x 1024
__global__ void scan_block_sums(const int* __restrict__ deg, int* __restrict__ bsum) {
    __shared__ int wsum[16];
    int tid = threadIdx.x;
    int i = blockIdx.x * 1024 + tid;
    int v = (i < NN) ? deg[i] : 0;
    // wave reduce
    #pragma unroll
    for (int d = 1; d < 64; d <<= 1) v += __shfl_xor(v, d);
    if ((tid & 63) == 0) wsum[tid >> 6] = v;
    __syncthreads();
    if (tid == 0) {
        int s = 0;
        #pragma unroll
        for (int w = 0; w < 16; w++) s += wsum[w];
        bsum[blockIdx.x] = s;
    }
}

__global__ void scan_bsum_serial(int* __restrict__ bsum, int nblocks) {
    if (threadIdx.x == 0 && blockIdx.x == 0) {
        int carry = 0;
        for (int i = 0; i < nblocks; i++) {
            int t = bsum[i];
            bsum[i] = carry;
            carry += t;
        }
    }
}

__global__ void scan_final(const int* __restrict__ deg, const int* __restrict__ bsum,
                           int* __restrict__ offs) {
    __shared__ int wsum[16];
    int tid = threadIdx.x, wid = tid >> 6, lane = tid & 63;
    int i = blockIdx.x * 1024 + tid;
    int v = (i < NN) ? deg[i] : 0;
    int incl = v;
    #pragma unroll
    for (int d = 1; d < 64; d <<= 1) {
        int t = __shfl_up(incl, d);
        if (lane >= d) incl += t;
    }
    if (lane == 63) wsum[wid] = incl;
    __syncthreads();
    if (wid == 0 && lane < 16) {
        int s = wsum[lane];
        #pragma unroll
        for (int d = 1; d < 16; d <<= 1) {
            int t = __shfl_up(s, d);
            if ((lane & 15) >= d) s += t;
        }
        wsum[lane] = s;   // inclusive scan of wave totals
    }
    __syncthreads();
    int woff = (wid > 0) ? wsum[wid - 1] : 0;
    if (i < NN) offs[i] = bsum[blockIdx.x] + woff + incl - v;   // exclusive
}

// scatter src values into segment order; offs becomes "segment end" array
__global__ void scatter_edges(const int* __restrict__ src, const int* __restrict__ dst,
                              int* __restrict__ offs, int* __restrict__ sorted_src) {
    int e = blockIdx.x * 256 + threadIdx.x;
    if (e < EE) {
        int pos = atomicAdd(&offs[dst[e]], 1);
        sorted_src[pos] = src[e];
    }
}

// ---------------------------------------------------------------------------
// Fused per-dst attention: scores + softmax + weighted aggregation.
// One wave per dst node; lane l owns elements {2l,2l+1}; head = l>>3.
// q and t may alias (q row read into regs before t row written).
// offs[n] = end of segment n (post-scatter); start = offs[n-1] (or 0).
// ---------------------------------------------------------------------------
__launch_bounds__(256, 4)
__global__ void fused_attn(const float* __restrict__ q, const float* __restrict__ k,
                           const float* __restrict__ v,
                           const int* __restrict__ offs, const int* __restrict__ sorted_src,
                           const float* __restrict__ rel_pri, float* __restrict__ t) {
    __shared__ float exbuf[4][CAP][8];
    int wave = threadIdx.x >> 6, lane = threadIdx.x & 63;
    int n = blockIdx.x * 4 + wave;
    if (n >= NN) return;
    int hh = lane >> 3;
    int start = (n > 0) ? offs[n - 1] : 0;
    int end = offs[n];
    int cnt = end - start;

    float2 q2 = *(const float2*)&q[(size_t)n * 128 + lane * 2];
    float scale = rel_pri[hh] * 0.25f;
    q2.x *= scale; q2.y *= scale;

    float denom = 0.f;
    for (int i = 0; i < cnt; i++) {
        int s = sorted_src[start + i];
        float2 k2 = *(const float2*)&k[(size_t)s * 128 + lane * 2];
        float p = q2.x * k2.x + q2.y * k2.y;
        p += __shfl_xor(p, 1);
        p += __shfl_xor(p, 2);
        p += __shfl_xor(p, 4);
        float ev = expf(p);
        denom += ev;
        if (i < CAP && (lane & 7) == 0) exbuf[wave][i][hh] = ev;
    }
    float inv = (cnt > 0) ? 1.f / denom : 0.f;

    float2 o2 = {0.f, 0.f};
    for (int i = 0; i < cnt; i++) {
        int s = sorted_src[start + i];
        float ev;
        if (i < CAP) {
            ev = exbuf[wave][i][hh];
        } else {  // rare fallback: recompute
            float2 k2 = *(const float2*)&k[(size_t)s * 128 + lane * 2];
            float p = q2.x * k2.x + q2.y * k2.y;
            p += __shfl_xor(p, 1);
            p += __shfl_xor(p, 2);
            p += __shfl_xor(p, 4);
            ev = expf(p);
        }
        float attn = ev * inv;
        float2 v2 = *(const float2*)&v[(size_t)s * 128 + lane * 2];
        o2.x = fmaf(v2.x, attn, o2.x);
        o2.y = fmaf(v2.y, attn, o2.y);
    }
    *(float2*)&t[(size_t)n * 128 + lane * 2] = o2;
}

// ---------------------------------------------------------------------------
extern "C" void kernel_launch(void* const* d_in, const int* in_sizes, int n_in,
                              void* d_out, int out_size, void* d_ws, size_t ws_size,
                              hipStream_t stream) {
    const float* h    = (const float*)d_in[0];
    const int*   src  = (const int*)d_in[1];
    const int*   dst  = (const int*)d_in[2];
    const float* Wk   = (const float*)d_in[3];
    const float* bk   = (const float*)d_in[4];
    const float* Wq   = (const float*)d_in[5];
    const float* bq   = (const float*)d_in[6];
    const float* Wv   = (const float*)d_in[7];
    const float* bv   = (const float*)d_in[8];
    const float* Wa   = (const float*)d_in[9];
    const float* ba   = (const float*)d_in[10];
    const float* rel_att = (const float*)d_in[11];
    const float* rel_msg = (const float*)d_in[12];
    const float* rel_pri = (const float*)d_in[13];
    const float* skip    = (const float*)d_in[14];
    float* out = (float*)d_out;

    float* ws  = (float*)d_ws;
    float* kbuf = ws;                          // N*D
    float* vbuf = kbuf + (size_t)NN * DD;      // N*D
    float* WqT = vbuf + (size_t)NN * DD;       // D*D
    float* WkT = WqT + DD * DD;
    float* WvT = WkT + DD * DD;
    float* WaT = WvT + DD * DD;
    float* bke = WaT + DD * DD;                // D
    float* bve = bke + DD;                     // D
    int* deg   = (int*)(bve + DD);             // N
    int* offs  = deg + NN;                     // N
    int* bsum  = offs + NN;                    // 128
    int* sorted_src = bsum + 128;              // E
    float* q = out;                            // q lives in d_out; t aliases q
    float* t = out;

    const int SCAN_BLOCKS = (NN + 1023) / 1024;  // 98

    prep_weights<<<dim3(64, 4), 256, 0, stream>>>(Wq, Wk, Wv, Wa, bk, bv,
                                                  rel_att, rel_msg,
                                                  WqT, WkT, WvT, WaT, bke, bve);
    // CSR build (independent of projections)
    hipMemsetAsync(deg, 0, (size_t)NN * sizeof(int), stream);
    hist_dst<<<(EE + 255) / 256, 256, 0, stream>>>(dst, deg);
    scan_block_sums<<<SCAN_BLOCKS, 1024, 0, stream>>>(deg, bsum);
    scan_bsum_serial<<<1, 64, 0, stream>>>(bsum, SCAN_BLOCKS);
    scan_final<<<SCAN_BLOCKS, 1024, 0, stream>>>(deg, bsum, offs);
    scatter_edges<<<(EE + 255) / 256, 256, 0, stream>>>(src, dst, offs, sorted_src);

    // projections
    gemm128<<<1024, 256, 0, stream>>>(h, WqT, bq, q, nullptr, nullptr);
    gemm128<<<1024, 256, 0, stream>>>(h, WkT, bke, kbuf, nullptr, nullptr);
    gemm128<<<1024, 256, 0, stream>>>(h, WvT, bve, vbuf, nullptr, nullptr);

    // fused attention (no atomics)
    fused_attn<<<(NN + 3) / 4, 256, 0, stream>>>(q, kbuf, vbuf, offs, sorted_src,
                                                 rel_pri, t);

    // final projection + skip-gate mix (in-place on d_out)
    gemm128<<<1024, 256, 0, stream>>>(t, WaT, ba, out, h, skip);
}

// Round 3
// 971.087 us; speedup vs baseline: 5.2508x; 2.7066x over previous
//
#include <hip/hip_runtime.h>
#include <hip/hip_bf16.h>
#include <math.h>

#define NN 100000
#define EE 1600000
#define DD 128
#define HH 8
#define CAP 64   // LDS-cached edges per node in fused_attn
#define LDW 136  // padded LDS row stride (bf16 elems) for 128-wide tiles

typedef short short8 __attribute__((ext_vector_type(8)));
typedef float f32x4 __attribute__((ext_vector_type(4)));

__device__ __forceinline__ unsigned short f2bf(float f) {  // RNE float->bf16 bits
    unsigned int u = __float_as_uint(f);
    u += 0x7fffu + ((u >> 16) & 1u);
    return (unsigned short)(u >> 16);
}
__device__ __forceinline__ float bf2f(unsigned short h) {
    return __uint_as_float((unsigned int)h << 16);
}
__device__ __forceinline__ void atomAddF(float* p, float v) { unsafeAtomicAdd(p, v); }

// ---------------------------------------------------------------------------
// Fold rel_att/rel_msg into Wk/Wv; emit all 4 weights in [j][c] order as
// bf16 hi/lo pairs (W ~= hi + lo to ~16-bit mantissa), plus effective biases.
// which: 0=q, 1=k(fold), 2=v(fold), 3=a
// ---------------------------------------------------------------------------
__global__ void prep_weights(const float* __restrict__ Wq, const float* __restrict__ Wk,
                             const float* __restrict__ Wv, const float* __restrict__ Wa,
                             const float* __restrict__ bq, const float* __restrict__ bk,
                             const float* __restrict__ bv, const float* __restrict__ ba,
                             const float* __restrict__ rel_att, const float* __restrict__ rel_msg,
                             unsigned short* __restrict__ WH, unsigned short* __restrict__ WL,
                             float* __restrict__ BE) {
    int o = blockIdx.x * 256 + threadIdx.x;   // [j][c], j=out col, c=in dim
    int j = o >> 7, c = o & 127;
    int which = blockIdx.y;
    float val;
    if (which == 0) {
        val = Wq[o];
        if (o < 128) BE[o] = bq[o];
    } else if (which == 3) {
        val = Wa[o];
        if (o < 128) BE[384 + o] = ba[o];
    } else {
        const float* rel = (which == 1) ? rel_att : rel_msg;
        const float* W   = (which == 1) ? Wk : Wv;
        const float* b   = (which == 1) ? bk : bv;
        int hh = j >> 4, e = j & 15;
        val = 0.f;
        #pragma unroll
        for (int d = 0; d < 16; d++)
            val += rel[hh * 256 + d * 16 + e] * W[(hh * 16 + d) * 128 + c];
        if (c == 0) {
            float bacc = 0.f;
            #pragma unroll
            for (int d = 0; d < 16; d++)
                bacc += b[hh * 16 + d] * rel[hh * 256 + d * 16 + e];
            BE[which * 128 + j] = bacc;
        }
    }
    unsigned short hi = f2bf(val);
    unsigned short lo = f2bf(val - bf2f(hi));
    WH[which * 16384 + o] = hi;
    WL[which * 16384 + o] = lo;
}

// ---------------------------------------------------------------------------
// MFMA GEMM: for wi in [0,nw): outs[wi][N,128] = x[N,128] @ W_wi.T + BE[wi]
// x converted to bf16 hi/lo in LDS once; W_wi staged hi/lo per phase.
// hi/lo split: acc = xh*Wh + xl*Wh + xh*Wl  (error ~2^-18 rel).
// mfma_f32_16x16x32_bf16 layouts (guide-verified):
//   A: lane holds A[m=lane&15][k=(lane>>4)*8 + j]
//   B: lane holds B[k=(lane>>4)*8 + j][n=lane&15]  (LDS stores W as [n][k])
//   C/D: col=lane&15, row=(lane>>4)*4 + reg
// If resid: out = alpha*(acc+bias) + (1-alpha)*resid, alpha=sigmoid(skip).
// In-place (x==out) safe: x-tile fully staged to LDS before any store.
// ---------------------------------------------------------------------------
__launch_bounds__(256, 1)
__global__ void gemm_mfma(const float* __restrict__ x,
                          const unsigned short* __restrict__ WH,
                          const unsigned short* __restrict__ WL,
                          const float* __restrict__ BE, int nw,
                          float* __restrict__ out0, float* __restrict__ out1,
                          float* __restrict__ out2,
                          const float* __restrict__ resid, const float* __restrict__ skip) {
    __shared__ unsigned short xh[128 * LDW];
    __shared__ unsigned short xl[128 * LDW];
    __shared__ unsigned short wh[128 * LDW];
    __shared__ unsigned short wl[128 * LDW];
    int tid = threadIdx.x;
    int base = blockIdx.x * 128;

    // stage x tile (128 rows) as bf16 hi/lo
    for (int i = tid; i < 128 * 32; i += 256) {
        int r = i >> 5, c4 = (i & 31) << 2;
        int row = base + r;
        float4 v;
        v.x = v.y = v.z = v.w = 0.f;
        if (row < NN) v = *(const float4*)&x[(size_t)row * 128 + c4];
        ushort4 h4, l4;
        h4.x = f2bf(v.x); l4.x = f2bf(v.x - bf2f(h4.x));
        h4.y = f2bf(v.y); l4.y = f2bf(v.y - bf2f(h4.y));
        h4.z = f2bf(v.z); l4.z = f2bf(v.z - bf2f(h4.z));
        h4.w = f2bf(v.w); l4.w = f2bf(v.w - bf2f(h4.w));
        *(ushort4*)&xh[r * LDW + c4] = h4;
        *(ushort4*)&xl[r * LDW + c4] = l4;
    }

    int wv = tid >> 6, lane = tid & 63;
    int lrow = lane & 15, quad = lane >> 4;
    float alpha = 1.f, beta = 0.f;
    if (resid) {
        float sv = skip[0];
        alpha = 1.f / (1.f + expf(-sv));
        beta = 1.f - alpha;
    }
    float* outs[3] = {out0, out1, out2};

    for (int wi = 0; wi < nw; wi++) {
        __syncthreads();   // protect prior-phase W readers (and x staging on wi=0)
        const unsigned short* WHp = WH + wi * 16384;
        const unsigned short* WLp = WL + wi * 16384;
        for (int i = tid; i < 128 * 16; i += 256) {
            int n = i >> 4, kq = (i & 15) << 3;
            *(uint4*)&wh[n * LDW + kq] = *(const uint4*)&WHp[n * 128 + kq];
            *(uint4*)&wl[n * LDW + kq] = *(const uint4*)&WLp[n * 128 + kq];
        }
        __syncthreads();

        f32x4 zero4 = {0.f, 0.f, 0.f, 0.f};
        f32x4 acc[2][8];
        #pragma unroll
        for (int a = 0; a < 2; a++)
            #pragma unroll
            for (int b = 0; b < 8; b++) acc[a][b] = zero4;

        int arow0 = (wv * 32 + lrow) * LDW;
        int arow1 = (wv * 32 + 16 + lrow) * LDW;
        #pragma unroll
        for (int kc = 0; kc < 4; kc++) {
            int koff = kc * 32 + quad * 8;
            short8 ah0 = *(const short8*)&xh[arow0 + koff];
            short8 ah1 = *(const short8*)&xh[arow1 + koff];
            short8 al0 = *(const short8*)&xl[arow0 + koff];
            short8 al1 = *(const short8*)&xl[arow1 + koff];
            #pragma unroll
            for (int nt = 0; nt < 8; nt++) {
                int brow = (nt * 16 + lrow) * LDW + koff;
                short8 bh = *(const short8*)&wh[brow];
                short8 bl = *(const short8*)&wl[brow];
                acc[0][nt] = __builtin_amdgcn_mfma_f32_16x16x32_bf16(ah0, bh, acc[0][nt], 0, 0, 0);
                acc[1][nt] = __builtin_amdgcn_mfma_f32_16x16x32_bf16(ah1, bh, acc[1][nt], 0, 0, 0);
                acc[0][nt] = __builtin_amdgcn_mfma_f32_16x16x32_bf16(al0, bh, acc[0][nt], 0, 0, 0);
                acc[1][nt] = __builtin_amdgcn_mfma_f32_16x16x32_bf16(al1, bh, acc[1][nt], 0, 0, 0);
                acc[0][nt] = __builtin_amdgcn_mfma_f32_16x16x32_bf16(ah0, bl, acc[0][nt], 0, 0, 0);
                acc[1][nt] = __builtin_amdgcn_mfma_f32_16x16x32_bf16(ah1, bl, acc[1][nt], 0, 0, 0);
            }
        }

        float* op = outs[wi];
        const float* be = BE + wi * 128;
        #pragma unroll
        for (int nt = 0; nt < 8; nt++) {
            int col = nt * 16 + lrow;
            float bb = be[col];
            #pragma unroll
            for (int mt = 0; mt < 2; mt++) {
                int r0 = base + wv * 32 + mt * 16 + quad * 4;
                #pragma unroll
                for (int rg = 0; rg < 4; rg++) {
                    int row = r0 + rg;
                    if (row < NN) {
                        float val = acc[mt][nt][rg] + bb;
                        if (resid) val = alpha * val + beta * resid[(size_t)row * 128 + col];
                        op[(size_t)row * 128 + col] = val;
                    }
                }
            }
        }
    }
}

// ------------------------- CSR build (counting sort) -----------------------
__global__ void hist_dst(const int* __restrict__ dst, int* __restrict__ deg) {
    int e = blockIdx.x * 256 + threadIdx.x;
    if (e < EE) atomicAdd(&deg[dst[e]], 1);
}

__global__ void scan_block_sums(const int* __restrict__ deg, int* __restrict__ bsum) {
    __shared__ int wsum[16];
    int tid = threadIdx.x;
    int i = blockIdx.x * 1024 + tid;
    int v = (i < NN) ? deg[i] : 0;
    #pragma unroll
    for (int d = 1; d < 64; d <<= 1) v += __shfl_xor(v, d);
    if ((tid & 63) == 0) wsum[tid >> 6] = v;
    __syncthreads();
    if (tid == 0) {
        int s = 0;
        #pragma unroll
        for (int w = 0; w < 16; w++) s += wsum[w];
        bsum[blockIdx.x] = s;
    }
}

__global__ void scan_bsum_serial(int* __restrict__ bsum, int nblocks) {
    if (threadIdx.x == 0 && blockIdx.x == 0) {
        int carry = 0;
        for (int i = 0; i < nblocks; i++) {
            int t = bsum[i];
            bsum[i] = carry;
            carry += t;
        }
    }
}

__global__ void scan_final(const int* __restrict__ deg, const int* __restrict__ bsum,
                           int* __restrict__ offs) {
    __shared__ int wsum[16];
    int tid = threadIdx.x, wid = tid >> 6, lane = tid & 63;
    int i = blockIdx.x * 1024 + tid;
    int v = (i < NN) ? deg[i] : 0;
    int incl = v;
    #pragma unroll
    for (int d = 1; d < 64; d <<= 1) {
        int t = __shfl_up(incl, d);
        if (lane >= d) incl += t;
    }
    if (lane == 63) wsum[wid] = incl;
    __syncthreads();
    if (wid == 0 && lane < 16) {
        int s = wsum[lane];
        #pragma unroll
        for (int d = 1; d < 16; d <<= 1) {
            int t = __shfl_up(s, d);
            if ((lane & 15) >= d) s += t;
        }
        wsum[lane] = s;
    }
    __syncthreads();
    int woff = (wid > 0) ? wsum[wid - 1] : 0;
    if (i < NN) offs[i] = bsum[blockIdx.x] + woff + incl - v;   // exclusive
}

__global__ void scatter_edges(const int* __restrict__ src, const int* __restrict__ dst,
                              int* __restrict__ offs, int* __restrict__ sorted_src) {
    int e = blockIdx.x * 256 + threadIdx.x;
    if (e < EE) {
        int pos = atomicAdd(&offs[dst[e]], 1);
        sorted_src[pos] = src[e];
    }
}

// ---------------------------------------------------------------------------
// Fused per-dst attention: scores + softmax + weighted aggregation.
// One wave per dst node; lane l owns elements {2l,2l+1}; head = l>>3.
// ---------------------------------------------------------------------------
__launch_bounds__(256, 4)
__global__ void fused_attn(const float* __restrict__ q, const float* __restrict__ k,
                           const float* __restrict__ v,
                           const int* __restrict__ offs, const int* __restrict__ sorted_src,
                           const float* __restrict__ rel_pri, float* __restrict__ t) {
    __shared__ float exbuf[4][CAP][8];
    int wave = threadIdx.x >> 6, lane = threadIdx.x & 63;
    int n = blockIdx.x * 4 + wave;
    if (n >= NN) return;
    int hh = lane >> 3;
    int start = (n > 0) ? offs[n - 1] : 0;
    int end = offs[n];
    int cnt = end - start;

    float2 q2 = *(const float2*)&q[(size_t)n * 128 + lane * 2];
    float scale = rel_pri[hh] * 0.25f;
    q2.x *= scale; q2.y *= scale;

    float denom = 0.f;
    for (int i = 0; i < cnt; i++) {
        int s = sorted_src[start + i];
        float2 k2 = *(const float2*)&k[(size_t)s * 128 + lane * 2];
        float p = q2.x * k2.x + q2.y * k2.y;
        p += __shfl_xor(p, 1);
        p += __shfl_xor(p, 2);
        p += __shfl_xor(p, 4);
        float ev = expf(p);
        denom += ev;
        if (i < CAP && (lane & 7) == 0) exbuf[wave][i][hh] = ev;
    }
    float inv = (cnt > 0) ? 1.f / denom : 0.f;

    float2 o2 = {0.f, 0.f};
    for (int i = 0; i < cnt; i++) {
        int s = sorted_src[start + i];
        float ev;
        if (i < CAP) {
            ev = exbuf[wave][i][hh];
        } else {
            float2 k2 = *(const float2*)&k[(size_t)s * 128 + lane * 2];
            float p = q2.x * k2.x + q2.y * k2.y;
            p += __shfl_xor(p, 1);
            p += __shfl_xor(p, 2);
            p += __shfl_xor(p, 4);
            ev = expf(p);
        }
        float attn = ev * inv;
        float2 v2 = *(const float2*)&v[(size_t)s * 128 + lane * 2];
        o2.x = fmaf(v2.x, attn, o2.x);
        o2.y = fmaf(v2.y, attn, o2.y);
    }
    *(float2*)&t[(size_t)n * 128 + lane * 2] = o2;
}

// ---------------------------------------------------------------------------
extern "C" void kernel_launch(void* const* d_in, const int* in_sizes, int n_in,
                              void* d_out, int out_size, void* d_ws, size_t ws_size,
                              hipStream_t stream) {
    const float* h    = (const float*)d_in[0];
    const int*   src  = (const int*)d_in[1];
    const int*   dst  = (const int*)d_in[2];
    const float* Wk   = (const float*)d_in[3];
    const float* bk   = (const float*)d_in[4];
    const float* Wq   = (const float*)d_in[5];
    const float* bq   = (const float*)d_in[6];
    const float* Wv   = (const float*)d_in[7];
    const float* bv   = (const float*)d_in[8];
    const float* Wa   = (const float*)d_in[9];
    const float* ba   = (const float*)d_in[10];
    const float* rel_att = (const float*)d_in[11];
    const float* rel_msg = (const float*)d_in[12];
    const float* rel_pri = (const float*)d_in[13];
    const float* skip    = (const float*)d_in[14];
    float* out = (float*)d_out;

    float* ws   = (float*)d_ws;
    float* kbuf = ws;                              // N*D
    float* vbuf = kbuf + (size_t)NN * DD;          // N*D
    float* BE   = vbuf + (size_t)NN * DD;          // 4*128
    int* deg    = (int*)(BE + 512);                // N
    int* offs   = deg + NN;                        // N
    int* bsum   = offs + NN;                       // 128
    int* sorted_src = bsum + 128;                  // E
    unsigned short* WH = (unsigned short*)(sorted_src + EE);  // 4*16384 bf16
    unsigned short* WL = WH + 4 * 16384;                      // 4*16384 bf16
    float* q = out;                                // q lives in d_out; t aliases q
    float* t = out;

    const int SCAN_BLOCKS = (NN + 1023) / 1024;    // 98
    const int GEMM_BLOCKS = (NN + 127) / 128;      // 782

    prep_weights<<<dim3(64, 4), 256, 0, stream>>>(Wq, Wk, Wv, Wa, bq, bk, bv, ba,
                                                  rel_att, rel_msg, WH, WL, BE);
    // CSR build (independent of projections)
    hipMemsetAsync(deg, 0, (size_t)NN * sizeof(int), stream);
    hist_dst<<<(EE + 255) / 256, 256, 0, stream>>>(dst, deg);
    scan_block_sums<<<SCAN_BLOCKS, 1024, 0, stream>>>(deg, bsum);
    scan_bsum_serial<<<1, 64, 0, stream>>>(bsum, SCAN_BLOCKS);
    scan_final<<<SCAN_BLOCKS, 1024, 0, stream>>>(deg, bsum, offs);
    scatter_edges<<<(EE + 255) / 256, 256, 0, stream>>>(src, dst, offs, sorted_src);

    // fused q|k|v projection (reads h once)
    gemm_mfma<<<GEMM_BLOCKS, 256, 0, stream>>>(h, WH, WL, BE, 3, q, kbuf, vbuf,
                                               nullptr, nullptr);
    // fused attention (no atomics)
    fused_attn<<<(NN + 3) / 4, 256, 0, stream>>>(q, kbuf, vbuf, offs, sorted_src,
                                                 rel_pri, t);
    // final projection + skip-gate mix (in-place on d_out)
    gemm_mfma<<<GEMM_BLOCKS, 256, 0, stream>>>(t, WH + 3 * 16384, WL + 3 * 16384,
                                               BE + 384, 1, out, nullptr, nullptr,
                                               h, skip);
}

// Round 5
// 842.905 us; speedup vs baseline: 6.0494x; 1.1521x over previous
//
#include <hip/hip_runtime.h>
#include <hip/hip_bf16.h>
#include <math.h>

#define NN 100000
#define EE 1600000
#define DD 128
#define HH 8
#define LDW 136  // padded LDS row stride (bf16 elems) for 128-wide tiles

typedef short short8 __attribute__((ext_vector_type(8)));
typedef float f32x4 __attribute__((ext_vector_type(4)));

__device__ __forceinline__ unsigned short f2bf(float f) {  // RNE float->bf16 bits
    unsigned int u = __float_as_uint(f);
    u += 0x7fffu + ((u >> 16) & 1u);
    return (unsigned short)(u >> 16);
}
__device__ __forceinline__ float bf2f(unsigned short h) {
    return __uint_as_float((unsigned int)h << 16);
}

// ---------------------------------------------------------------------------
// Fold rel_att/rel_msg into Wk/Wv; emit all 4 weights in [j][c] order as
// bf16 hi/lo pairs, plus effective biases.
// which: 0=q, 1=k(fold), 2=v(fold), 3=a
// ---------------------------------------------------------------------------
__global__ void prep_weights(const float* __restrict__ Wq, const float* __restrict__ Wk,
                             const float* __restrict__ Wv, const float* __restrict__ Wa,
                             const float* __restrict__ bq, const float* __restrict__ bk,
                             const float* __restrict__ bv, const float* __restrict__ ba,
                             const float* __restrict__ rel_att, const float* __restrict__ rel_msg,
                             unsigned short* __restrict__ WH, unsigned short* __restrict__ WL,
                             float* __restrict__ BE) {
    int o = blockIdx.x * 256 + threadIdx.x;   // [j][c], j=out col, c=in dim
    int j = o >> 7, c = o & 127;
    int which = blockIdx.y;
    float val;
    if (which == 0) {
        val = Wq[o];
        if (o < 128) BE[o] = bq[o];
    } else if (which == 3) {
        val = Wa[o];
        if (o < 128) BE[384 + o] = ba[o];
    } else {
        const float* rel = (which == 1) ? rel_att : rel_msg;
        const float* W   = (which == 1) ? Wk : Wv;
        const float* b   = (which == 1) ? bk : bv;
        int hh = j >> 4, e = j & 15;
        val = 0.f;
        #pragma unroll
        for (int d = 0; d < 16; d++)
            val += rel[hh * 256 + d * 16 + e] * W[(hh * 16 + d) * 128 + c];
        if (c == 0) {
            float bacc = 0.f;
            #pragma unroll
            for (int d = 0; d < 16; d++)
                bacc += b[hh * 16 + d] * rel[hh * 256 + d * 16 + e];
            BE[which * 128 + j] = bacc;
        }
    }
    unsigned short hi = f2bf(val);
    unsigned short lo = f2bf(val - bf2f(hi));
    WH[which * 16384 + o] = hi;
    WL[which * 16384 + o] = lo;
}

// ---------------------------------------------------------------------------
// MFMA GEMM with bf16 hi/lo split (R3-proven). In-place safe.
// ---------------------------------------------------------------------------
__launch_bounds__(256, 1)
__global__ void gemm_mfma(const float* __restrict__ x,
                          const unsigned short* __restrict__ WH,
                          const unsigned short* __restrict__ WL,
                          const float* __restrict__ BE, int nw,
                          float* __restrict__ out0, float* __restrict__ out1,
                          float* __restrict__ out2,
                          const float* __restrict__ resid, const float* __restrict__ skip) {
    __shared__ unsigned short xh[128 * LDW];
    __shared__ unsigned short xl[128 * LDW];
    __shared__ unsigned short wh[128 * LDW];
    __shared__ unsigned short wl[128 * LDW];
    int tid = threadIdx.x;
    int base = blockIdx.x * 128;

    for (int i = tid; i < 128 * 32; i += 256) {
        int r = i >> 5, c4 = (i & 31) << 2;
        int row = base + r;
        float4 v;
        v.x = v.y = v.z = v.w = 0.f;
        if (row < NN) v = *(const float4*)&x[(size_t)row * 128 + c4];
        ushort4 h4, l4;
        h4.x = f2bf(v.x); l4.x = f2bf(v.x - bf2f(h4.x));
        h4.y = f2bf(v.y); l4.y = f2bf(v.y - bf2f(h4.y));
        h4.z = f2bf(v.z); l4.z = f2bf(v.z - bf2f(h4.z));
        h4.w = f2bf(v.w); l4.w = f2bf(v.w - bf2f(h4.w));
        *(ushort4*)&xh[r * LDW + c4] = h4;
        *(ushort4*)&xl[r * LDW + c4] = l4;
    }

    int wv = tid >> 6, lane = tid & 63;
    int lrow = lane & 15, quad = lane >> 4;
    float alpha = 1.f, beta = 0.f;
    if (resid) {
        float sv = skip[0];
        alpha = 1.f / (1.f + expf(-sv));
        beta = 1.f - alpha;
    }
    float* outs[3] = {out0, out1, out2};

    for (int wi = 0; wi < nw; wi++) {
        __syncthreads();
        const unsigned short* WHp = WH + wi * 16384;
        const unsigned short* WLp = WL + wi * 16384;
        for (int i = tid; i < 128 * 16; i += 256) {
            int n = i >> 4, kq = (i & 15) << 3;
            *(uint4*)&wh[n * LDW + kq] = *(const uint4*)&WHp[n * 128 + kq];
            *(uint4*)&wl[n * LDW + kq] = *(const uint4*)&WLp[n * 128 + kq];
        }
        __syncthreads();

        f32x4 zero4 = {0.f, 0.f, 0.f, 0.f};
        f32x4 acc[2][8];
        #pragma unroll
        for (int a = 0; a < 2; a++)
            #pragma unroll
            for (int b = 0; b < 8; b++) acc[a][b] = zero4;

        int arow0 = (wv * 32 + lrow) * LDW;
        int arow1 = (wv * 32 + 16 + lrow) * LDW;
        #pragma unroll
        for (int kc = 0; kc < 4; kc++) {
            int koff = kc * 32 + quad * 8;
            short8 ah0 = *(const short8*)&xh[arow0 + koff];
            short8 ah1 = *(const short8*)&xh[arow1 + koff];
            short8 al0 = *(const short8*)&xl[arow0 + koff];
            short8 al1 = *(const short8*)&xl[arow1 + koff];
            #pragma unroll
            for (int nt = 0; nt < 8; nt++) {
                int brow = (nt * 16 + lrow) * LDW + koff;
                short8 bh = *(const short8*)&wh[brow];
                short8 bl = *(const short8*)&wl[brow];
                acc[0][nt] = __builtin_amdgcn_mfma_f32_16x16x32_bf16(ah0, bh, acc[0][nt], 0, 0, 0);
                acc[1][nt] = __builtin_amdgcn_mfma_f32_16x16x32_bf16(ah1, bh, acc[1][nt], 0, 0, 0);
                acc[0][nt] = __builtin_amdgcn_mfma_f32_16x16x32_bf16(al0, bh, acc[0][nt], 0, 0, 0);
                acc[1][nt] = __builtin_amdgcn_mfma_f32_16x16x32_bf16(al1, bh, acc[1][nt], 0, 0, 0);
                acc[0][nt] = __builtin_amdgcn_mfma_f32_16x16x32_bf16(ah0, bl, acc[0][nt], 0, 0, 0);
                acc[1][nt] = __builtin_amdgcn_mfma_f32_16x16x32_bf16(ah1, bl, acc[1][nt], 0, 0, 0);
            }
        }

        float* op = outs[wi];
        const float* be = BE + wi * 128;
        #pragma unroll
        for (int nt = 0; nt < 8; nt++) {
            int col = nt * 16 + lrow;
            float bb = be[col];
            #pragma unroll
            for (int mt = 0; mt < 2; mt++) {
                int r0 = base + wv * 32 + mt * 16 + quad * 4;
                #pragma unroll
                for (int rg = 0; rg < 4; rg++) {
                    int row = r0 + rg;
                    if (row < NN) {
                        float val = acc[mt][nt][rg] + bb;
                        if (resid) val = alpha * val + beta * resid[(size_t)row * 128 + col];
                        op[(size_t)row * 128 + col] = val;
                    }
                }
            }
        }
    }
}

// ------------------------- CSR build (counting sort) -----------------------
__global__ void hist_dst(const int* __restrict__ dst, int* __restrict__ deg) {
    int e = blockIdx.x * 256 + threadIdx.x;
    if (e < EE) atomicAdd(&deg[dst[e]], 1);
}

__global__ void scan_block_sums(const int* __restrict__ deg, int* __restrict__ bsum) {
    __shared__ int wsum[16];
    int tid = threadIdx.x;
    int i = blockIdx.x * 1024 + tid;
    int v = (i < NN) ? deg[i] : 0;
    #pragma unroll
    for (int d = 1; d < 64; d <<= 1) v += __shfl_xor(v, d);
    if ((tid & 63) == 0) wsum[tid >> 6] = v;
    __syncthreads();
    if (tid == 0) {
        int s = 0;
        #pragma unroll
        for (int w = 0; w < 16; w++) s += wsum[w];
        bsum[blockIdx.x] = s;
    }
}

// proven-correct serial scan of 98 block sums (R3 baseline)
__global__ void scan_bsum_serial(int* __restrict__ bsum, int nblocks) {
    if (threadIdx.x == 0 && blockIdx.x == 0) {
        int carry = 0;
        for (int i = 0; i < nblocks; i++) {
            int t = bsum[i];
            bsum[i] = carry;
            carry += t;
        }
    }
}

__global__ void scan_final(const int* __restrict__ deg, const int* __restrict__ bsum,
                           int* __restrict__ offs) {
    __shared__ int wsum[16];
    int tid = threadIdx.x, wid = tid >> 6, lane = tid & 63;
    int i = blockIdx.x * 1024 + tid;
    int v = (i < NN) ? deg[i] : 0;
    int incl = v;
    #pragma unroll
    for (int d = 1; d < 64; d <<= 1) {
        int t = __shfl_up(incl, d);
        if (lane >= d) incl += t;
    }
    if (lane == 63) wsum[wid] = incl;
    __syncthreads();
    if (wid == 0 && lane < 16) {
        int s = wsum[lane];
        #pragma unroll
        for (int d = 1; d < 16; d <<= 1) {
            int t = __shfl_up(s, d);
            if ((lane & 15) >= d) s += t;
        }
        wsum[lane] = s;
    }
    __syncthreads();
    int woff = (wid > 0) ? wsum[wid - 1] : 0;
    if (i < NN) offs[i] = bsum[blockIdx.x] + woff + incl - v;   // exclusive
}

__global__ void scatter_edges(const int* __restrict__ src, const int* __restrict__ dst,
                              int* __restrict__ offs, int* __restrict__ sorted_src) {
    int e = blockIdx.x * 256 + threadIdx.x;
    if (e < EE) {
        int pos = atomicAdd(&offs[dst[e]], 1);
        sorted_src[pos] = src[e];
    }
}

// ---------------------------------------------------------------------------
// Fused per-dst attention, SINGLE PASS (R3 lane layout, proven):
//   t[n] = (sum_e exp(s_e) * v[src_e]) / (sum_e exp(s_e))
// One wave per node; lane l owns elements {2l,2l+1}; head = l>>3.
// 2 edges per iteration: 4 independent float2 loads in flight, no divergence.
// q and t may alias (q row read before t row written; k,v are separate).
// ---------------------------------------------------------------------------
__launch_bounds__(256, 4)
__global__ void fused_attn(const float* __restrict__ q, const float* __restrict__ k,
                           const float* __restrict__ v,
                           const int* __restrict__ offs, const int* __restrict__ sorted_src,
                           const float* __restrict__ rel_pri, float* __restrict__ t) {
    int wave = threadIdx.x >> 6, lane = threadIdx.x & 63;
    int n = blockIdx.x * 4 + wave;
    if (n >= NN) return;
    int hh = lane >> 3;
    int start = (n > 0) ? offs[n - 1] : 0;
    int cnt = offs[n] - start;

    float2 q2 = *(const float2*)&q[(size_t)n * 128 + lane * 2];
    float scale = rel_pri[hh] * 0.25f;
    q2.x *= scale; q2.y *= scale;

    float2 o2 = {0.f, 0.f};
    float denom = 0.f;

    int i = 0;
    for (; i + 2 <= cnt; i += 2) {
        int s0 = sorted_src[start + i];
        int s1 = sorted_src[start + i + 1];
        float2 k0 = *(const float2*)&k[(size_t)s0 * 128 + lane * 2];
        float2 k1 = *(const float2*)&k[(size_t)s1 * 128 + lane * 2];
        float2 v0 = *(const float2*)&v[(size_t)s0 * 128 + lane * 2];
        float2 v1 = *(const float2*)&v[(size_t)s1 * 128 + lane * 2];
        float p0 = q2.x * k0.x + q2.y * k0.y;
        float p1 = q2.x * k1.x + q2.y * k1.y;
        p0 += __shfl_xor(p0, 1);
        p1 += __shfl_xor(p1, 1);
        p0 += __shfl_xor(p0, 2);
        p1 += __shfl_xor(p1, 2);
        p0 += __shfl_xor(p0, 4);
        p1 += __shfl_xor(p1, 4);
        float e0 = expf(p0);
        float e1 = expf(p1);
        denom += e0 + e1;
        o2.x = fmaf(v0.x, e0, o2.x);
        o2.y = fmaf(v0.y, e0, o2.y);
        o2.x = fmaf(v1.x, e1, o2.x);
        o2.y = fmaf(v1.y, e1, o2.y);
    }
    if (i < cnt) {   // tail edge
        int s0 = sorted_src[start + i];
        float2 k0 = *(const float2*)&k[(size_t)s0 * 128 + lane * 2];
        float2 v0 = *(const float2*)&v[(size_t)s0 * 128 + lane * 2];
        float p0 = q2.x * k0.x + q2.y * k0.y;
        p0 += __shfl_xor(p0, 1);
        p0 += __shfl_xor(p0, 2);
        p0 += __shfl_xor(p0, 4);
        float e0 = expf(p0);
        denom += e0;
        o2.x = fmaf(v0.x, e0, o2.x);
        o2.y = fmaf(v0.y, e0, o2.y);
    }

    float inv = (cnt > 0) ? 1.f / denom : 0.f;
    o2.x *= inv;
    o2.y *= inv;
    *(float2*)&t[(size_t)n * 128 + lane * 2] = o2;
}

// ---------------------------------------------------------------------------
extern "C" void kernel_launch(void* const* d_in, const int* in_sizes, int n_in,
                              void* d_out, int out_size, void* d_ws, size_t ws_size,
                              hipStream_t stream) {
    const float* h    = (const float*)d_in[0];
    const int*   src  = (const int*)d_in[1];
    const int*   dst  = (const int*)d_in[2];
    const float* Wk   = (const float*)d_in[3];
    const float* bk   = (const float*)d_in[4];
    const float* Wq   = (const float*)d_in[5];
    const float* bq   = (const float*)d_in[6];
    const float* Wv   = (const float*)d_in[7];
    const float* bv   = (const float*)d_in[8];
    const float* Wa   = (const float*)d_in[9];
    const float* ba   = (const float*)d_in[10];
    const float* rel_att = (const float*)d_in[11];
    const float* rel_msg = (const float*)d_in[12];
    const float* rel_pri = (const float*)d_in[13];
    const float* skip    = (const float*)d_in[14];
    float* out = (float*)d_out;

    float* ws   = (float*)d_ws;
    float* kbuf = ws;                              // N*D
    float* vbuf = kbuf + (size_t)NN * DD;          // N*D
    float* BE   = vbuf + (size_t)NN * DD;          // 4*128
    int* deg    = (int*)(BE + 512);                // N
    int* offs   = deg + NN;                        // N
    int* bsum   = offs + NN;                       // 128
    int* sorted_src = bsum + 128;                  // E
    unsigned short* WH = (unsigned short*)(sorted_src + EE);  // 4*16384 bf16
    unsigned short* WL = WH + 4 * 16384;                      // 4*16384 bf16
    float* q = out;                                // q lives in d_out; t aliases q
    float* t = out;

    const int SCAN_BLOCKS = (NN + 1023) / 1024;    // 98
    const int GEMM_BLOCKS = (NN + 127) / 128;      // 782

    prep_weights<<<dim3(64, 4), 256, 0, stream>>>(Wq, Wk, Wv, Wa, bq, bk, bv, ba,
                                                  rel_att, rel_msg, WH, WL, BE);
    // CSR build
    hipMemsetAsync(deg, 0, (size_t)NN * sizeof(int), stream);
    hist_dst<<<(EE + 255) / 256, 256, 0, stream>>>(dst, deg);
    scan_block_sums<<<SCAN_BLOCKS, 1024, 0, stream>>>(deg, bsum);
    scan_bsum_serial<<<1, 64, 0, stream>>>(bsum, SCAN_BLOCKS);
    scan_final<<<SCAN_BLOCKS, 1024, 0, stream>>>(deg, bsum, offs);
    scatter_edges<<<(EE + 255) / 256, 256, 0, stream>>>(src, dst, offs, sorted_src);

    // fused q|k|v projection (reads h once)
    gemm_mfma<<<GEMM_BLOCKS, 256, 0, stream>>>(h, WH, WL, BE, 3, q, kbuf, vbuf,
                                               nullptr, nullptr);
    // fused single-pass attention (no atomics)
    fused_attn<<<(NN + 3) / 4, 256, 0, stream>>>(q, kbuf, vbuf, offs, sorted_src,
                                                 rel_pri, t);
    // final projection + skip-gate mix (in-place on d_out)
    gemm_mfma<<<GEMM_BLOCKS, 256, 0, stream>>>(t, WH + 3 * 16384, WL + 3 * 16384,
                                               BE + 384, 1, out, nullptr, nullptr,
                                               h, skip);
}

// Round 6
// 647.399 us; speedup vs baseline: 7.8762x; 1.3020x over previous
//
#include <hip/hip_runtime.h>
#include <hip/hip_bf16.h>
#include <math.h>

#define NN 100000
#define EE 1600000
#define DD 128
#define HH 8
#define LDW 136  // padded LDS row stride (bf16 elems) for 128-wide W tiles

typedef short short8 __attribute__((ext_vector_type(8)));
typedef float f32x4 __attribute__((ext_vector_type(4)));

__device__ __forceinline__ unsigned short f2bf(float f) {  // RNE float->bf16 bits
    unsigned int u = __float_as_uint(f);
    u += 0x7fffu + ((u >> 16) & 1u);
    return (unsigned short)(u >> 16);
}
__device__ __forceinline__ float bf2f(unsigned short h) {
    return __uint_as_float((unsigned int)h << 16);
}
// 8 floats -> bf16 hi + residual-lo vectors
__device__ __forceinline__ void cvt8(const float4& a, const float4& b,
                                     short8& h8, short8& l8) {
    float vals[8] = {a.x, a.y, a.z, a.w, b.x, b.y, b.z, b.w};
    #pragma unroll
    for (int j = 0; j < 8; j++) {
        unsigned short hi = f2bf(vals[j]);
        h8[j] = (short)hi;
        l8[j] = (short)f2bf(vals[j] - bf2f(hi));
    }
}

// ---------------------------------------------------------------------------
// Fold rel_att/rel_msg into Wk/Wv; emit all 4 weights in [j][c] order as
// bf16 hi/lo pairs, plus effective biases. which: 0=q, 1=k, 2=v, 3=a
// ---------------------------------------------------------------------------
__global__ void prep_weights(const float* __restrict__ Wq, const float* __restrict__ Wk,
                             const float* __restrict__ Wv, const float* __restrict__ Wa,
                             const float* __restrict__ bq, const float* __restrict__ bk,
                             const float* __restrict__ bv, const float* __restrict__ ba,
                             const float* __restrict__ rel_att, const float* __restrict__ rel_msg,
                             unsigned short* __restrict__ WH, unsigned short* __restrict__ WL,
                             float* __restrict__ BE) {
    int o = blockIdx.x * 256 + threadIdx.x;   // [j][c], j=out col, c=in dim
    int j = o >> 7, c = o & 127;
    int which = blockIdx.y;
    float val;
    if (which == 0) {
        val = Wq[o];
        if (o < 128) BE[o] = bq[o];
    } else if (which == 3) {
        val = Wa[o];
        if (o < 128) BE[384 + o] = ba[o];
    } else {
        const float* rel = (which == 1) ? rel_att : rel_msg;
        const float* W   = (which == 1) ? Wk : Wv;
        const float* b   = (which == 1) ? bk : bv;
        int hh = j >> 4, e = j & 15;
        val = 0.f;
        #pragma unroll
        for (int d = 0; d < 16; d++)
            val += rel[hh * 256 + d * 16 + e] * W[(hh * 16 + d) * 128 + c];
        if (c == 0) {
            float bacc = 0.f;
            #pragma unroll
            for (int d = 0; d < 16; d++)
                bacc += b[hh * 16 + d] * rel[hh * 256 + d * 16 + e];
            BE[which * 128 + j] = bacc;
        }
    }
    unsigned short hi = f2bf(val);
    unsigned short lo = f2bf(val - bf2f(hi));
    WH[which * 16384 + o] = hi;
    WL[which * 16384 + o] = lo;
}

// ---------------------------------------------------------------------------
// Register-A MFMA GEMM, bf16 hi/lo split (acc = xh*Wh + xl*Wh + xh*Wl).
// Each wave holds its 32 x-rows as A-fragments in VGPRs (loaded once from
// global, converted in-reg); LDS holds only W hi/lo -> 2 blocks/CU.
// wi==0 epilogue: fp32 to out0 (+ optional skip-gate mix with resid).
// wi>=1 epilogue: bf16 into packed kv[row][256] at (wi-1)*128 + col.
// Fragment layouts (guide-verified, same as R3):
//   A: lane holds A[m=lane&15][k=quad*8+j]
//   B: lane holds B[k=quad*8+j][n=lane&15]  (LDS stores W as [n][k])
//   C/D: col=lane&15, row=quad*4+reg
// In-place (x==out0) safe: x rows are in registers before any store.
// ---------------------------------------------------------------------------
__launch_bounds__(256, 2)
__global__ void gemm_reg(const float* __restrict__ x,
                         const unsigned short* __restrict__ WH,
                         const unsigned short* __restrict__ WL,
                         const float* __restrict__ BE, int nw,
                         float* __restrict__ out0, unsigned short* __restrict__ kvout,
                         const float* __restrict__ resid, const float* __restrict__ skip) {
    __shared__ unsigned short wh[128 * LDW];
    __shared__ unsigned short wl[128 * LDW];
    int tid = threadIdx.x;
    int wv = tid >> 6, lane = tid & 63;
    int lrow = lane & 15, quad = lane >> 4;
    int base = blockIdx.x * 128;

    // ---- load this wave's 32 x-rows into A-fragment registers (hi/lo) ----
    short8 ah[2][4], al[2][4];
    float4 fz = {0.f, 0.f, 0.f, 0.f};
    #pragma unroll
    for (int mt = 0; mt < 2; mt++) {
        int row = base + wv * 32 + mt * 16 + lrow;
        const float* xr = x + (size_t)row * 128;
        bool ok = (row < NN);
        #pragma unroll
        for (int kc = 0; kc < 4; kc++) {
            int off = kc * 32 + quad * 8;
            float4 a = ok ? *(const float4*)&xr[off] : fz;
            float4 b = ok ? *(const float4*)&xr[off + 4] : fz;
            cvt8(a, b, ah[mt][kc], al[mt][kc]);
        }
    }

    float alpha = 1.f, beta = 0.f;
    if (resid) {
        float sv = skip[0];
        alpha = 1.f / (1.f + expf(-sv));
        beta = 1.f - alpha;
    }

    for (int wi = 0; wi < nw; wi++) {
        __syncthreads();   // prior-phase W readers done
        const unsigned short* WHp = WH + wi * 16384;
        const unsigned short* WLp = WL + wi * 16384;
        for (int i = tid; i < 128 * 16; i += 256) {
            int n = i >> 4, kq = (i & 15) << 3;
            *(uint4*)&wh[n * LDW + kq] = *(const uint4*)&WHp[n * 128 + kq];
            *(uint4*)&wl[n * LDW + kq] = *(const uint4*)&WLp[n * 128 + kq];
        }
        __syncthreads();

        f32x4 zero4 = {0.f, 0.f, 0.f, 0.f};
        f32x4 acc[2][8];
        #pragma unroll
        for (int a = 0; a < 2; a++)
            #pragma unroll
            for (int b = 0; b < 8; b++) acc[a][b] = zero4;

        #pragma unroll
        for (int kc = 0; kc < 4; kc++) {
            int koff = kc * 32 + quad * 8;
            #pragma unroll
            for (int nt = 0; nt < 8; nt++) {
                int brow = (nt * 16 + lrow) * LDW + koff;
                short8 bh = *(const short8*)&wh[brow];
                short8 bl = *(const short8*)&wl[brow];
                acc[0][nt] = __builtin_amdgcn_mfma_f32_16x16x32_bf16(ah[0][kc], bh, acc[0][nt], 0, 0, 0);
                acc[1][nt] = __builtin_amdgcn_mfma_f32_16x16x32_bf16(ah[1][kc], bh, acc[1][nt], 0, 0, 0);
                acc[0][nt] = __builtin_amdgcn_mfma_f32_16x16x32_bf16(al[0][kc], bh, acc[0][nt], 0, 0, 0);
                acc[1][nt] = __builtin_amdgcn_mfma_f32_16x16x32_bf16(al[1][kc], bh, acc[1][nt], 0, 0, 0);
                acc[0][nt] = __builtin_amdgcn_mfma_f32_16x16x32_bf16(ah[0][kc], bl, acc[0][nt], 0, 0, 0);
                acc[1][nt] = __builtin_amdgcn_mfma_f32_16x16x32_bf16(ah[1][kc], bl, acc[1][nt], 0, 0, 0);
            }
        }

        const float* be = BE + wi * 128;
        #pragma unroll
        for (int nt = 0; nt < 8; nt++) {
            int col = nt * 16 + lrow;
            float bb = be[col];
            #pragma unroll
            for (int mt = 0; mt < 2; mt++) {
                int r0 = base + wv * 32 + mt * 16 + quad * 4;
                #pragma unroll
                for (int rg = 0; rg < 4; rg++) {
                    int row = r0 + rg;
                    if (row < NN) {
                        float val = acc[mt][nt][rg] + bb;
                        if (wi == 0) {
                            if (resid) val = alpha * val + beta * resid[(size_t)row * 128 + col];
                            out0[(size_t)row * 128 + col] = val;
                        } else {
                            kvout[(size_t)row * 256 + (wi - 1) * 128 + col] = f2bf(val);
                        }
                    }
                }
            }
        }
    }
}

// ------------------------- CSR build (counting sort) -----------------------
__global__ void hist_dst(const int* __restrict__ dst, int* __restrict__ deg) {
    int e = blockIdx.x * 256 + threadIdx.x;
    if (e < EE) atomicAdd(&deg[dst[e]], 1);
}

__global__ void scan_block_sums(const int* __restrict__ deg, int* __restrict__ bsum) {
    __shared__ int wsum[16];
    int tid = threadIdx.x;
    int i = blockIdx.x * 1024 + tid;
    int v = (i < NN) ? deg[i] : 0;
    #pragma unroll
    for (int d = 1; d < 64; d <<= 1) v += __shfl_xor(v, d);
    if ((tid & 63) == 0) wsum[tid >> 6] = v;
    __syncthreads();
    if (tid == 0) {
        int s = 0;
        #pragma unroll
        for (int w = 0; w < 16; w++) s += wsum[w];
        bsum[blockIdx.x] = s;
    }
}

// proven-correct serial scan of 98 block sums
__global__ void scan_bsum_serial(int* __restrict__ bsum, int nblocks) {
    if (threadIdx.x == 0 && blockIdx.x == 0) {
        int carry = 0;
        for (int i = 0; i < nblocks; i++) {
            int t = bsum[i];
            bsum[i] = carry;
            carry += t;
        }
    }
}

__global__ void scan_final(const int* __restrict__ deg, const int* __restrict__ bsum,
                           int* __restrict__ offs) {
    __shared__ int wsum[16];
    int tid = threadIdx.x, wid = tid >> 6, lane = tid & 63;
    int i = blockIdx.x * 1024 + tid;
    int v = (i < NN) ? deg[i] : 0;
    int incl = v;
    #pragma unroll
    for (int d = 1; d < 64; d <<= 1) {
        int t = __shfl_up(incl, d);
        if (lane >= d) incl += t;
    }
    if (lane == 63) wsum[wid] = incl;
    __syncthreads();
    if (wid == 0 && lane < 16) {
        int s = wsum[lane];
        #pragma unroll
        for (int d = 1; d < 16; d <<= 1) {
            int t = __shfl_up(s, d);
            if ((lane & 15) >= d) s += t;
        }
        wsum[lane] = s;
    }
    __syncthreads();
    int woff = (wid > 0) ? wsum[wid - 1] : 0;
    if (i < NN) offs[i] = bsum[blockIdx.x] + woff + incl - v;   // exclusive
}

__global__ void scatter_edges(const int* __restrict__ src, const int* __restrict__ dst,
                              int* __restrict__ offs, int* __restrict__ sorted_src) {
    int e = blockIdx.x * 256 + threadIdx.x;
    if (e < EE) {
        int pos = atomicAdd(&offs[dst[e]], 1);
        sorted_src[pos] = src[e];
    }
}

// ---------------------------------------------------------------------------
// Fused per-dst attention, single pass, bf16 packed kv[n][256] (k:0-127,
// v:128-255). One wave per node; lane l owns elems {2l,2l+1}; head = l>>3.
// 2 edges/iter; q fp32 (may alias t: q row read before t row written).
// ---------------------------------------------------------------------------
__launch_bounds__(256, 4)
__global__ void fused_attn(const float* __restrict__ q,
                           const unsigned short* __restrict__ kv,
                           const int* __restrict__ offs, const int* __restrict__ sorted_src,
                           const float* __restrict__ rel_pri, float* __restrict__ t) {
    int wave = threadIdx.x >> 6, lane = threadIdx.x & 63;
    int n = blockIdx.x * 4 + wave;
    if (n >= NN) return;
    int hh = lane >> 3;
    int start = (n > 0) ? offs[n - 1] : 0;
    int cnt = offs[n] - start;

    float2 q2 = *(const float2*)&q[(size_t)n * 128 + lane * 2];
    float scale = rel_pri[hh] * 0.25f;
    q2.x *= scale; q2.y *= scale;

    float2 o2 = {0.f, 0.f};
    float denom = 0.f;

    int i = 0;
    for (; i + 2 <= cnt; i += 2) {
        int s0 = sorted_src[start + i];
        int s1 = sorted_src[start + i + 1];
        const unsigned short* r0 = kv + (size_t)s0 * 256;
        const unsigned short* r1 = kv + (size_t)s1 * 256;
        unsigned int kb0 = *(const unsigned int*)(r0 + lane * 2);
        unsigned int kb1 = *(const unsigned int*)(r1 + lane * 2);
        unsigned int vb0 = *(const unsigned int*)(r0 + 128 + lane * 2);
        unsigned int vb1 = *(const unsigned int*)(r1 + 128 + lane * 2);
        float p0 = q2.x * bf2f((unsigned short)(kb0 & 0xffff))
                 + q2.y * bf2f((unsigned short)(kb0 >> 16));
        float p1 = q2.x * bf2f((unsigned short)(kb1 & 0xffff))
                 + q2.y * bf2f((unsigned short)(kb1 >> 16));
        p0 += __shfl_xor(p0, 1);
        p1 += __shfl_xor(p1, 1);
        p0 += __shfl_xor(p0, 2);
        p1 += __shfl_xor(p1, 2);
        p0 += __shfl_xor(p0, 4);
        p1 += __shfl_xor(p1, 4);
        float e0 = expf(p0);
        float e1 = expf(p1);
        denom += e0 + e1;
        o2.x = fmaf(bf2f((unsigned short)(vb0 & 0xffff)), e0, o2.x);
        o2.y = fmaf(bf2f((unsigned short)(vb0 >> 16)),    e0, o2.y);
        o2.x = fmaf(bf2f((unsigned short)(vb1 & 0xffff)), e1, o2.x);
        o2.y = fmaf(bf2f((unsigned short)(vb1 >> 16)),    e1, o2.y);
    }
    if (i < cnt) {   // tail edge
        int s0 = sorted_src[start + i];
        const unsigned short* r0 = kv + (size_t)s0 * 256;
        unsigned int kb0 = *(const unsigned int*)(r0 + lane * 2);
        unsigned int vb0 = *(const unsigned int*)(r0 + 128 + lane * 2);
        float p0 = q2.x * bf2f((unsigned short)(kb0 & 0xffff))
                 + q2.y * bf2f((unsigned short)(kb0 >> 16));
        p0 += __shfl_xor(p0, 1);
        p0 += __shfl_xor(p0, 2);
        p0 += __shfl_xor(p0, 4);
        float e0 = expf(p0);
        denom += e0;
        o2.x = fmaf(bf2f((unsigned short)(vb0 & 0xffff)), e0, o2.x);
        o2.y = fmaf(bf2f((unsigned short)(vb0 >> 16)),    e0, o2.y);
    }

    float inv = (cnt > 0) ? 1.f / denom : 0.f;
    o2.x *= inv;
    o2.y *= inv;
    *(float2*)&t[(size_t)n * 128 + lane * 2] = o2;
}

// ---------------------------------------------------------------------------
extern "C" void kernel_launch(void* const* d_in, const int* in_sizes, int n_in,
                              void* d_out, int out_size, void* d_ws, size_t ws_size,
                              hipStream_t stream) {
    const float* h    = (const float*)d_in[0];
    const int*   src  = (const int*)d_in[1];
    const int*   dst  = (const int*)d_in[2];
    const float* Wk   = (const float*)d_in[3];
    const float* bk   = (const float*)d_in[4];
    const float* Wq   = (const float*)d_in[5];
    const float* bq   = (const float*)d_in[6];
    const float* Wv   = (const float*)d_in[7];
    const float* bv   = (const float*)d_in[8];
    const float* Wa   = (const float*)d_in[9];
    const float* ba   = (const float*)d_in[10];
    const float* rel_att = (const float*)d_in[11];
    const float* rel_msg = (const float*)d_in[12];
    const float* rel_pri = (const float*)d_in[13];
    const float* skip    = (const float*)d_in[14];
    float* out = (float*)d_out;

    unsigned short* kvbuf = (unsigned short*)d_ws;            // N*256 bf16
    float* BE   = (float*)(kvbuf + (size_t)NN * 256);         // 4*128
    int* deg    = (int*)(BE + 512);                           // N
    int* offs   = deg + NN;                                   // N
    int* bsum   = offs + NN;                                  // 128
    int* sorted_src = bsum + 128;                             // E
    unsigned short* WH = (unsigned short*)(sorted_src + EE);  // 4*16384 bf16
    unsigned short* WL = WH + 4 * 16384;                      // 4*16384 bf16
    float* q = out;                                // q lives in d_out; t aliases q
    float* t = out;

    const int SCAN_BLOCKS = (NN + 1023) / 1024;    // 98
    const int GEMM_BLOCKS = (NN + 127) / 128;      // 782

    prep_weights<<<dim3(64, 4), 256, 0, stream>>>(Wq, Wk, Wv, Wa, bq, bk, bv, ba,
                                                  rel_att, rel_msg, WH, WL, BE);
    // CSR build
    hipMemsetAsync(deg, 0, (size_t)NN * sizeof(int), stream);
    hist_dst<<<(EE + 255) / 256, 256, 0, stream>>>(dst, deg);
    scan_block_sums<<<SCAN_BLOCKS, 1024, 0, stream>>>(deg, bsum);
    scan_bsum_serial<<<1, 64, 0, stream>>>(bsum, SCAN_BLOCKS);
    scan_final<<<SCAN_BLOCKS, 1024, 0, stream>>>(deg, bsum, offs);
    scatter_edges<<<(EE + 255) / 256, 256, 0, stream>>>(src, dst, offs, sorted_src);

    // fused q|k|v projection: q fp32 -> d_out, k/v bf16 -> packed kv
    gemm_reg<<<GEMM_BLOCKS, 256, 0, stream>>>(h, WH, WL, BE, 3, q, kvbuf,
                                              nullptr, nullptr);
    // fused single-pass attention (no atomics)
    fused_attn<<<(NN + 3) / 4, 256, 0, stream>>>(q, kvbuf, offs, sorted_src,
                                                 rel_pri, t);
    // final projection + skip-gate mix (in-place on d_out)
    gemm_reg<<<GEMM_BLOCKS, 256, 0, stream>>>(t, WH + 3 * 16384, WL + 3 * 16384,
                                              BE + 384, 1, out, nullptr,
                                              h, skip);
}

// Round 7
// 636.399 us; speedup vs baseline: 8.0123x; 1.0173x over previous
//
#include <hip/hip_runtime.h>
#include <hip/hip_bf16.h>
#include <math.h>

#define NN 100000
#define EE 1600000
#define DD 128
#define HH 8
#define LDW 136  // padded LDS row stride (bf16 elems) for 128-wide W tiles

typedef short short8 __attribute__((ext_vector_type(8)));
typedef float f32x4 __attribute__((ext_vector_type(4)));

__device__ __forceinline__ unsigned short f2bf(float f) {  // RNE float->bf16 bits
    unsigned int u = __float_as_uint(f);
    u += 0x7fffu + ((u >> 16) & 1u);
    return (unsigned short)(u >> 16);
}
__device__ __forceinline__ float bf2f(unsigned short h) {
    return __uint_as_float((unsigned int)h << 16);
}
// 8 floats -> bf16 hi + residual-lo vectors
__device__ __forceinline__ void cvt8(const float4& a, const float4& b,
                                     short8& h8, short8& l8) {
    float vals[8] = {a.x, a.y, a.z, a.w, b.x, b.y, b.z, b.w};
    #pragma unroll
    for (int j = 0; j < 8; j++) {
        unsigned short hi = f2bf(vals[j]);
        h8[j] = (short)hi;
        l8[j] = (short)f2bf(vals[j] - bf2f(hi));
    }
}

// ---------------------------------------------------------------------------
// Fold rel_att/rel_msg into Wk/Wv; emit all 4 weights in [j][c] order as
// bf16 hi/lo pairs, plus effective biases. which: 0=q, 1=k, 2=v, 3=a
// ---------------------------------------------------------------------------
__global__ void prep_weights(const float* __restrict__ Wq, const float* __restrict__ Wk,
                             const float* __restrict__ Wv, const float* __restrict__ Wa,
                             const float* __restrict__ bq, const float* __restrict__ bk,
                             const float* __restrict__ bv, const float* __restrict__ ba,
                             const float* __restrict__ rel_att, const float* __restrict__ rel_msg,
                             unsigned short* __restrict__ WH, unsigned short* __restrict__ WL,
                             float* __restrict__ BE) {
    int o = blockIdx.x * 256 + threadIdx.x;   // [j][c], j=out col, c=in dim
    int j = o >> 7, c = o & 127;
    int which = blockIdx.y;
    float val;
    if (which == 0) {
        val = Wq[o];
        if (o < 128) BE[o] = bq[o];
    } else if (which == 3) {
        val = Wa[o];
        if (o < 128) BE[384 + o] = ba[o];
    } else {
        const float* rel = (which == 1) ? rel_att : rel_msg;
        const float* W   = (which == 1) ? Wk : Wv;
        const float* b   = (which == 1) ? bk : bv;
        int hh = j >> 4, e = j & 15;
        val = 0.f;
        #pragma unroll
        for (int d = 0; d < 16; d++)
            val += rel[hh * 256 + d * 16 + e] * W[(hh * 16 + d) * 128 + c];
        if (c == 0) {
            float bacc = 0.f;
            #pragma unroll
            for (int d = 0; d < 16; d++)
                bacc += b[hh * 16 + d] * rel[hh * 256 + d * 16 + e];
            BE[which * 128 + j] = bacc;
        }
    }
    unsigned short hi = f2bf(val);
    unsigned short lo = f2bf(val - bf2f(hi));
    WH[which * 16384 + o] = hi;
    WL[which * 16384 + o] = lo;
}

// ---------------------------------------------------------------------------
// Register-A MFMA GEMM, bf16 hi/lo split (R6-proven). In-place safe.
// ---------------------------------------------------------------------------
__launch_bounds__(256, 2)
__global__ void gemm_reg(const float* __restrict__ x,
                         const unsigned short* __restrict__ WH,
                         const unsigned short* __restrict__ WL,
                         const float* __restrict__ BE, int nw,
                         float* __restrict__ out0, unsigned short* __restrict__ kvout,
                         const float* __restrict__ resid, const float* __restrict__ skip) {
    __shared__ unsigned short wh[128 * LDW];
    __shared__ unsigned short wl[128 * LDW];
    int tid = threadIdx.x;
    int wv = tid >> 6, lane = tid & 63;
    int lrow = lane & 15, quad = lane >> 4;
    int base = blockIdx.x * 128;

    // ---- load this wave's 32 x-rows into A-fragment registers (hi/lo) ----
    short8 ah[2][4], al[2][4];
    float4 fz = {0.f, 0.f, 0.f, 0.f};
    #pragma unroll
    for (int mt = 0; mt < 2; mt++) {
        int row = base + wv * 32 + mt * 16 + lrow;
        const float* xr = x + (size_t)row * 128;
        bool ok = (row < NN);
        #pragma unroll
        for (int kc = 0; kc < 4; kc++) {
            int off = kc * 32 + quad * 8;
            float4 a = ok ? *(const float4*)&xr[off] : fz;
            float4 b = ok ? *(const float4*)&xr[off + 4] : fz;
            cvt8(a, b, ah[mt][kc], al[mt][kc]);
        }
    }

    float alpha = 1.f, beta = 0.f;
    if (resid) {
        float sv = skip[0];
        alpha = 1.f / (1.f + expf(-sv));
        beta = 1.f - alpha;
    }

    for (int wi = 0; wi < nw; wi++) {
        __syncthreads();   // prior-phase W readers done
        const unsigned short* WHp = WH + wi * 16384;
        const unsigned short* WLp = WL + wi * 16384;
        for (int i = tid; i < 128 * 16; i += 256) {
            int n = i >> 4, kq = (i & 15) << 3;
            *(uint4*)&wh[n * LDW + kq] = *(const uint4*)&WHp[n * 128 + kq];
            *(uint4*)&wl[n * LDW + kq] = *(const uint4*)&WLp[n * 128 + kq];
        }
        __syncthreads();

        f32x4 zero4 = {0.f, 0.f, 0.f, 0.f};
        f32x4 acc[2][8];
        #pragma unroll
        for (int a = 0; a < 2; a++)
            #pragma unroll
            for (int b = 0; b < 8; b++) acc[a][b] = zero4;

        #pragma unroll
        for (int kc = 0; kc < 4; kc++) {
            #pragma unroll
            for (int nt = 0; nt < 8; nt++) {
                int koff = kc * 32 + quad * 8;
                int brow = (nt * 16 + lrow) * LDW + koff;
                short8 bh = *(const short8*)&wh[brow];
                short8 bl = *(const short8*)&wl[brow];
                acc[0][nt] = __builtin_amdgcn_mfma_f32_16x16x32_bf16(ah[0][kc], bh, acc[0][nt], 0, 0, 0);
                acc[1][nt] = __builtin_amdgcn_mfma_f32_16x16x32_bf16(ah[1][kc], bh, acc[1][nt], 0, 0, 0);
                acc[0][nt] = __builtin_amdgcn_mfma_f32_16x16x32_bf16(al[0][kc], bh, acc[0][nt], 0, 0, 0);
                acc[1][nt] = __builtin_amdgcn_mfma_f32_16x16x32_bf16(al[1][kc], bh, acc[1][nt], 0, 0, 0);
                acc[0][nt] = __builtin_amdgcn_mfma_f32_16x16x32_bf16(ah[0][kc], bl, acc[0][nt], 0, 0, 0);
                acc[1][nt] = __builtin_amdgcn_mfma_f32_16x16x32_bf16(ah[1][kc], bl, acc[1][nt], 0, 0, 0);
            }
        }

        const float* be = BE + wi * 128;
        #pragma unroll
        for (int nt = 0; nt < 8; nt++) {
            int col = nt * 16 + lrow;
            float bb = be[col];
            #pragma unroll
            for (int mt = 0; mt < 2; mt++) {
                int r0 = base + wv * 32 + mt * 16 + quad * 4;
                #pragma unroll
                for (int rg = 0; rg < 4; rg++) {
                    int row = r0 + rg;
                    if (row < NN) {
                        float val = acc[mt][nt][rg] + bb;
                        if (wi == 0) {
                            if (resid) val = alpha * val + beta * resid[(size_t)row * 128 + col];
                            out0[(size_t)row * 128 + col] = val;
                        } else {
                            kvout[(size_t)row * 256 + (wi - 1) * 128 + col] = f2bf(val);
                        }
                    }
                }
            }
        }
    }
}

// ------------------------- CSR build (counting sort) -----------------------
__global__ void hist_dst(const int* __restrict__ dst, int* __restrict__ deg) {
    int e = blockIdx.x * 256 + threadIdx.x;
    if (e < EE) atomicAdd(&deg[dst[e]], 1);
}

__global__ void scan_block_sums(const int* __restrict__ deg, int* __restrict__ bsum) {
    __shared__ int wsum[16];
    int tid = threadIdx.x;
    int i = blockIdx.x * 1024 + tid;
    int v = (i < NN) ? deg[i] : 0;
    #pragma unroll
    for (int d = 1; d < 64; d <<= 1) v += __shfl_xor(v, d);
    if ((tid & 63) == 0) wsum[tid >> 6] = v;
    __syncthreads();
    if (tid == 0) {
        int s = 0;
        #pragma unroll
        for (int w = 0; w < 16; w++) s += wsum[w];
        bsum[blockIdx.x] = s;
    }
}

// parallel exclusive scan of <=128 block sums: LDS Hillis-Steele, 128 thr
__global__ void scan_bsum_block(int* __restrict__ bsum, int n) {
    __shared__ int buf[2][128];
    int tIdx = threadIdx.x;
    int v = (tIdx < n) ? bsum[tIdx] : 0;
    buf[0][tIdx] = v;
    __syncthreads();
    int srcb = 0;
    #pragma unroll
    for (int d = 1; d < 128; d <<= 1) {
        int val = buf[srcb][tIdx];
        if (tIdx >= d) val += buf[srcb][tIdx - d];
        buf[1 - srcb][tIdx] = val;
        __syncthreads();
        srcb = 1 - srcb;
    }
    if (tIdx < n) bsum[tIdx] = buf[srcb][tIdx] - v;   // exclusive
}

__global__ void scan_final(const int* __restrict__ deg, const int* __restrict__ bsum,
                           int* __restrict__ offs) {
    __shared__ int wsum[16];
    int tid = threadIdx.x, wid = tid >> 6, lane = tid & 63;
    int i = blockIdx.x * 1024 + tid;
    int v = (i < NN) ? deg[i] : 0;
    int incl = v;
    #pragma unroll
    for (int d = 1; d < 64; d <<= 1) {
        int t = __shfl_up(incl, d);
        if (lane >= d) incl += t;
    }
    if (lane == 63) wsum[wid] = incl;
    __syncthreads();
    if (wid == 0 && lane < 16) {
        int s = wsum[lane];
        #pragma unroll
        for (int d = 1; d < 16; d <<= 1) {
            int t = __shfl_up(s, d);
            if ((lane & 15) >= d) s += t;
        }
        wsum[lane] = s;
    }
    __syncthreads();
    int woff = (wid > 0) ? wsum[wid - 1] : 0;
    if (i < NN) offs[i] = bsum[blockIdx.x] + woff + incl - v;   // exclusive
}

__global__ void scatter_edges(const int* __restrict__ src, const int* __restrict__ dst,
                              int* __restrict__ offs, int* __restrict__ sorted_src) {
    int e = blockIdx.x * 256 + threadIdx.x;
    if (e < EE) {
        int pos = atomicAdd(&offs[dst[e]], 1);
        sorted_src[pos] = src[e];
    }
}

// ---------------------------------------------------------------------------
// Fused per-dst attention, single pass, bf16 packed kv[n][256].
// One wave per node. 4 elems/lane: sl=lane&31 owns elems {4sl..4sl+3},
// head = sl>>2; the two half-waves process edges 2i and 2i+1.
// Divergence-free: all 64 lanes active every iteration; the odd-cnt tail is
// a duplicated edge with weight 0 (index clamped); ids loaded directly
// (uniform per half-wave) -- no shfl broadcast, no divergent shfl.
// q fp32 (may alias t: q row read before t row written).
// ---------------------------------------------------------------------------
__launch_bounds__(256, 4)
__global__ void fused_attn(const float* __restrict__ q,
                           const unsigned short* __restrict__ kv,
                           const int* __restrict__ offs, const int* __restrict__ sorted_src,
                           const float* __restrict__ rel_pri, float* __restrict__ t) {
    int wave = threadIdx.x >> 6, lane = threadIdx.x & 63;
    int n = blockIdx.x * 4 + wave;
    if (n >= NN) return;
    int half = lane >> 5;
    int sl = lane & 31;
    int hh = sl >> 2;
    int start = (n > 0) ? offs[n - 1] : 0;
    int cnt = offs[n] - start;

    float4 q4 = *(const float4*)&q[(size_t)n * 128 + sl * 4];
    float scale = rel_pri[hh] * 0.25f;
    q4.x *= scale; q4.y *= scale; q4.z *= scale; q4.w *= scale;

    float4 o4 = {0.f, 0.f, 0.f, 0.f};
    float denom = 0.f;

    int nIter = (cnt + 1) >> 1;
    #pragma unroll 2
    for (int it = 0; it < nIter; it++) {
        int j = 2 * it + half;
        float wgt = (j < cnt) ? 1.f : 0.f;
        int jj = (j < cnt) ? j : (cnt - 1);
        int s = sorted_src[start + jj];
        const unsigned short* r = kv + (size_t)s * 256;
        uint2 kb = *(const uint2*)(r + sl * 4);
        uint2 vb = *(const uint2*)(r + 128 + sl * 4);
        float p = q4.x * bf2f((unsigned short)(kb.x & 0xffff))
                + q4.y * bf2f((unsigned short)(kb.x >> 16))
                + q4.z * bf2f((unsigned short)(kb.y & 0xffff))
                + q4.w * bf2f((unsigned short)(kb.y >> 16));
        p += __shfl_xor(p, 1);
        p += __shfl_xor(p, 2);
        float e = expf(p) * wgt;
        denom += e;
        o4.x = fmaf(bf2f((unsigned short)(vb.x & 0xffff)), e, o4.x);
        o4.y = fmaf(bf2f((unsigned short)(vb.x >> 16)),    e, o4.y);
        o4.z = fmaf(bf2f((unsigned short)(vb.y & 0xffff)), e, o4.z);
        o4.w = fmaf(bf2f((unsigned short)(vb.y >> 16)),    e, o4.w);
    }

    // combine the two halves (all 64 lanes active)
    denom += __shfl_xor(denom, 32);
    o4.x += __shfl_xor(o4.x, 32);
    o4.y += __shfl_xor(o4.y, 32);
    o4.z += __shfl_xor(o4.z, 32);
    o4.w += __shfl_xor(o4.w, 32);

    if (half == 0) {
        float inv = (cnt > 0) ? 1.f / denom : 0.f;
        o4.x *= inv; o4.y *= inv; o4.z *= inv; o4.w *= inv;
        *(float4*)&t[(size_t)n * 128 + sl * 4] = o4;
    }
}

// ---------------------------------------------------------------------------
extern "C" void kernel_launch(void* const* d_in, const int* in_sizes, int n_in,
                              void* d_out, int out_size, void* d_ws, size_t ws_size,
                              hipStream_t stream) {
    const float* h    = (const float*)d_in[0];
    const int*   src  = (const int*)d_in[1];
    const int*   dst  = (const int*)d_in[2];
    const float* Wk   = (const float*)d_in[3];
    const float* bk   = (const float*)d_in[4];
    const float* Wq   = (const float*)d_in[5];
    const float* bq   = (const float*)d_in[6];
    const float* Wv   = (const float*)d_in[7];
    const float* bv   = (const float*)d_in[8];
    const float* Wa   = (const float*)d_in[9];
    const float* ba   = (const float*)d_in[10];
    const float* rel_att = (const float*)d_in[11];
    const float* rel_msg = (const float*)d_in[12];
    const float* rel_pri = (const float*)d_in[13];
    const float* skip    = (const float*)d_in[14];
    float* out = (float*)d_out;

    unsigned short* kvbuf = (unsigned short*)d_ws;            // N*256 bf16
    float* BE   = (float*)(kvbuf + (size_t)NN * 256);         // 4*128
    int* deg    = (int*)(BE + 512);                           // N
    int* offs   = deg + NN;                                   // N
    int* bsum   = offs + NN;                                  // 128
    int* sorted_src = bsum + 128;                             // E
    unsigned short* WH = (unsigned short*)(sorted_src + EE);  // 4*16384 bf16
    unsigned short* WL = WH + 4 * 16384;                      // 4*16384 bf16
    float* q = out;                                // q lives in d_out; t aliases q
    float* t = out;

    const int SCAN_BLOCKS = (NN + 1023) / 1024;    // 98
    const int GEMM_BLOCKS = (NN + 127) / 128;      // 782

    prep_weights<<<dim3(64, 4), 256, 0, stream>>>(Wq, Wk, Wv, Wa, bq, bk, bv, ba,
                                                  rel_att, rel_msg, WH, WL, BE);
    // CSR build
    hipMemsetAsync(deg, 0, (size_t)NN * sizeof(int), stream);
    hist_dst<<<(EE + 255) / 256, 256, 0, stream>>>(dst, deg);
    scan_block_sums<<<SCAN_BLOCKS, 1024, 0, stream>>>(deg, bsum);
    scan_bsum_block<<<1, 128, 0, stream>>>(bsum, SCAN_BLOCKS);
    scan_final<<<SCAN_BLOCKS, 1024, 0, stream>>>(deg, bsum, offs);
    scatter_edges<<<(EE + 255) / 256, 256, 0, stream>>>(src, dst, offs, sorted_src);

    // fused q|k|v projection: q fp32 -> d_out, k/v bf16 -> packed kv
    gemm_reg<<<GEMM_BLOCKS, 256, 0, stream>>>(h, WH, WL, BE, 3, q, kvbuf,
                                              nullptr, nullptr);
    // fused single-pass attention (no atomics)
    fused_attn<<<(NN + 3) / 4, 256, 0, stream>>>(q, kvbuf, offs, sorted_src,
                                                 rel_pri, t);
    // final projection + skip-gate mix (in-place on d_out)
    gemm_reg<<<GEMM_BLOCKS, 256, 0, stream>>>(t, WH + 3 * 16384, WL + 3 * 16384,
                                              BE + 384, 1, out, nullptr,
                                              h, skip);
}